// Round 7
// baseline (270.899 us; speedup 1.0000x reference)
//
#include <hip/hip_runtime.h>
#include <hip/hip_bf16.h>

// ---------------------------------------------------------------------------
// SparseKnowledgeAttention: q=ego@Wq.T+bq; k=(side*rel)@Wk.T+bk; v=side@Wv.T+bv
// scores=q@k.T/16 -> top16/row -> softmax -> weighted gather of v.
// fp16x3 split-precision MFMA (f32-exact scores), swapped operands
// (S^T = K·Q^T -> candidates lane-local). LDS-staged K tiles (BN=32) via
// global_load_lds with pre-swizzled source; 3 independent MFMA chains;
// Q fragments PINNED in registers (anti-rematerialization asm); per-lane
// register top-16 + small LDS survivor stack drained every group with
// ballot-free counted loop. grid 512 = 2 blocks/CU; split pinned per XCD.
// ---------------------------------------------------------------------------

#define EMB 256
#define NEGO 8192
#define NSIDE 8192
#define TOPKK 16
#define NSPLIT 8
#define SPLITLEN (NSIDE / NSPLIT)   // 1024
#define BM 128                      // ego rows per block (4 waves x 32)
#define BN 32                       // side rows per group
#define NGRP (SPLITLEN / BN)        // 32 groups per block
#define CAP 16                      // stack capacity (alloc 17: slop slot)

typedef _Float16 f16x8 __attribute__((ext_vector_type(8)));
typedef float f32x16 __attribute__((ext_vector_type(16)));

#define NEG_BIG (-3.402823466e38f)

__device__ __forceinline__ void gload_lds16(const _Float16* g, _Float16* l) {
    __builtin_amdgcn_global_load_lds((const __attribute__((address_space(1))) void*)g,
                                     (__attribute__((address_space(3))) void*)l, 16, 0, 0);
}

__device__ __forceinline__ void split8(const float* xv, f16x8& hi, f16x8& lo) {
#pragma unroll
    for (int j = 0; j < 8; ++j) {
        float x = xv[j];
        _Float16 h = (_Float16)x;
        hi[j] = h;
        lo[j] = (_Float16)(x - (float)h);
    }
}

// ---------------------------------------------------------------------------
// Projection kernel: C = X @ W.T + b  via fp16x3 MFMA. z = 0:q, 1:k, 2:v.
// grid (64, 3), block 256. Outputs: q,k as linear f16 hi/lo pairs; v as f32.
// ---------------------------------------------------------------------------
__global__ __launch_bounds__(256, 1) void proj_kernel(
    const float* __restrict__ ego, const float* __restrict__ side, const float* __restrict__ rel,
    const float* __restrict__ Wq, const float* __restrict__ bq,
    const float* __restrict__ Wk, const float* __restrict__ bk,
    const float* __restrict__ Wv, const float* __restrict__ bv,
    _Float16* __restrict__ qh, _Float16* __restrict__ ql,
    _Float16* __restrict__ kh, _Float16* __restrict__ kl,
    float* __restrict__ vout)
{
    __shared__ __align__(16) _Float16 Wh[64 * 256];   // 32KB, chunk-swizzled
    __shared__ __align__(16) _Float16 Wl[64 * 256];   // 32KB

    const int z = blockIdx.y;
    const float* X; const float* W; const float* bias;
    if (z == 0)      { X = ego;  W = Wq; bias = bq; }
    else if (z == 1) { X = side; W = Wk; bias = bk; }
    else             { X = side; W = Wv; bias = bv; }

    const int tid = threadIdx.x, lane = tid & 63, wave = tid >> 6;
    const int hk = lane >> 5, r = lane & 31;
    const int arow = blockIdx.x * BM + wave * 32 + r;

    f16x8 ah[16], al[16];
#pragma unroll
    for (int kst = 0; kst < 16; ++kst) {
        float xv[8];
        const float* p = X + arow * EMB + kst * 16 + hk * 8;
        const float4 x0 = *(const float4*)p;
        const float4 x1 = *(const float4*)(p + 4);
        xv[0]=x0.x; xv[1]=x0.y; xv[2]=x0.z; xv[3]=x0.w;
        xv[4]=x1.x; xv[5]=x1.y; xv[6]=x1.z; xv[7]=x1.w;
        if (z == 1) {
            const float* pr = rel + arow * EMB + kst * 16 + hk * 8;
            const float4 r0 = *(const float4*)pr;
            const float4 r1 = *(const float4*)(pr + 4);
            xv[0]*=r0.x; xv[1]*=r0.y; xv[2]*=r0.z; xv[3]*=r0.w;
            xv[4]*=r1.x; xv[5]*=r1.y; xv[6]*=r1.z; xv[7]*=r1.w;
        }
        split8(xv, ah[kst], al[kst]);
    }

    for (int nt = 0; nt < 4; ++nt) {
        __syncthreads();
#pragma unroll
        for (int i = 0; i < 8; ++i) {
            const int rowi = wave * 16 + i * 2 + hk;
            const int c = r;
            const float* wp = W + (nt * 64 + rowi) * EMB + ((c ^ (rowi & 31)) << 3);
            float xv[8];
            const float4 w0 = *(const float4*)wp;
            const float4 w1 = *(const float4*)(wp + 4);
            xv[0]=w0.x; xv[1]=w0.y; xv[2]=w0.z; xv[3]=w0.w;
            xv[4]=w1.x; xv[5]=w1.y; xv[6]=w1.z; xv[7]=w1.w;
            f16x8 h8, l8;
            split8(xv, h8, l8);
            *(f16x8*)&Wh[rowi * 256 + c * 8] = h8;
            *(f16x8*)&Wl[rowi * 256 + c * 8] = l8;
        }
        __syncthreads();

        f32x16 acc0 = {}, acc1 = {};
#pragma unroll
        for (int kst = 0; kst < 16; ++kst) {
            const int cc = kst * 2 + hk;
            const f16x8 bh0 = *(const f16x8*)&Wh[r * 256 + ((cc ^ r) << 3)];
            const f16x8 bl0 = *(const f16x8*)&Wl[r * 256 + ((cc ^ r) << 3)];
            const f16x8 bh1 = *(const f16x8*)&Wh[(32 + r) * 256 + ((cc ^ r) << 3)];
            const f16x8 bl1 = *(const f16x8*)&Wl[(32 + r) * 256 + ((cc ^ r) << 3)];
            acc0 = __builtin_amdgcn_mfma_f32_32x32x16_f16(ah[kst], bh0, acc0, 0, 0, 0);
            acc0 = __builtin_amdgcn_mfma_f32_32x32x16_f16(al[kst], bh0, acc0, 0, 0, 0);
            acc0 = __builtin_amdgcn_mfma_f32_32x32x16_f16(ah[kst], bl0, acc0, 0, 0, 0);
            acc1 = __builtin_amdgcn_mfma_f32_32x32x16_f16(ah[kst], bh1, acc1, 0, 0, 0);
            acc1 = __builtin_amdgcn_mfma_f32_32x32x16_f16(al[kst], bh1, acc1, 0, 0, 0);
            acc1 = __builtin_amdgcn_mfma_f32_32x32x16_f16(ah[kst], bl1, acc1, 0, 0, 0);
        }

#pragma unroll
        for (int reg = 0; reg < 16; ++reg) {
            const int crow = (reg & 3) + 8 * (reg >> 2) + 4 * hk;
            const int grow = blockIdx.x * BM + wave * 32 + crow;
            const int col0 = nt * 64 + r;
            const int col1 = nt * 64 + 32 + r;
            const float v0 = acc0[reg] + bias[col0];
            const float v1 = acc1[reg] + bias[col1];
            if (z < 2) {
                _Float16* oh = (z == 0) ? qh : kh;
                _Float16* ol = (z == 0) ? ql : kl;
                _Float16 h0 = (_Float16)v0;
                oh[grow * EMB + col0] = h0;
                ol[grow * EMB + col0] = (_Float16)(v0 - (float)h0);
                _Float16 h1 = (_Float16)v1;
                oh[grow * EMB + col1] = h1;
                ol[grow * EMB + col1] = (_Float16)(v1 - (float)h1);
            } else {
                vout[grow * EMB + col0] = v0;
                vout[grow * EMB + col1] = v1;
            }
        }
    }
}

// ---------------------------------------------------------------------------
// Fused scores + top-16. grid 512 (split = blk&7 -> XCD-pinned), block 256.
// ---------------------------------------------------------------------------
__global__ __launch_bounds__(256, 2) void scores_topk_kernel(
    const _Float16* __restrict__ qh, const _Float16* __restrict__ ql,
    const _Float16* __restrict__ kh, const _Float16* __restrict__ kl,
    float* __restrict__ part_sc, int* __restrict__ part_id)
{
    __shared__ __align__(16) _Float16 Bh[BN * 256];        // 16KB swizzled k-tile (hi)
    __shared__ __align__(16) _Float16 Bl[BN * 256];        // 16KB (lo)
    __shared__ unsigned long long stk[(CAP + 1) * 256];    // 34.8KB survivor stacks

    const int tid = threadIdx.x, lane = tid & 63, wave = tid >> 6;
    const int hk = lane >> 5, r = lane & 31;
    const int split = blockIdx.x & 7;          // XCD-pinned K-split
    const int bx = blockIdx.x >> 3;            // ego block 0..63
    const int qbase = bx * BM + wave * 32;
    const int rowoff0 = 4 * hk;

    // Per-lane register top-16 (distinct sentinels: value-keyed replace-min).
    float tkS[16]; int tkC[16];
#pragma unroll
    for (int j = 0; j < 16; ++j) { tkS[j] = -3.0e38f - (float)j * 1.0e30f; tkC[j] = 0x7fffffff; }
    float curmin = NEG_BIG;
    int cnt = 0;

    // Q fragments (row qbase+r) in registers — exact B-operand layout.
    f16x8 ah[16], al[16];
#pragma unroll
    for (int kst = 0; kst < 16; ++kst) {
        ah[kst] = *(const f16x8*)(qh + (qbase + r) * EMB + kst * 16 + hk * 8);
        al[kst] = *(const f16x8*)(ql + (qbase + r) * EMB + kst * 16 + hk * 8);
    }
    // PIN: make fragments opaque so the compiler cannot rematerialize the
    // global loads inside the group loop (round-6 VGPR=128 proved it did).
#pragma unroll
    for (int kst = 0; kst < 16; ++kst) {
        asm volatile("" : "+v"(ah[kst]), "+v"(al[kst]));
    }

    auto minTree = [&]() {
        float m0 = fminf(tkS[0], tkS[1]),  m1 = fminf(tkS[2], tkS[3]);
        float m2 = fminf(tkS[4], tkS[5]),  m3 = fminf(tkS[6], tkS[7]);
        float m4 = fminf(tkS[8], tkS[9]),  m5 = fminf(tkS[10], tkS[11]);
        float m6 = fminf(tkS[12], tkS[13]), m7 = fminf(tkS[14], tkS[15]);
        m0 = fminf(m0, m1); m2 = fminf(m2, m3); m4 = fminf(m4, m5); m6 = fminf(m6, m7);
        curmin = fminf(fminf(m0, m2), fminf(m4, m6));
    };

    // Ballot-free drain: wave-max(cnt) once, counted loop, next-entry preload
    // (slop slot CAP makes e+1 always in-bounds).
    auto rebuild = [&]() {
        int mc = cnt;
#pragma unroll
        for (int o = 32; o; o >>= 1) { const int t = __shfl_xor(mc, o); mc = t > mc ? t : mc; }
        unsigned long long v = stk[tid];
        for (int e = 0; e < mc; ++e) {
            const unsigned long long vn = stk[(e + 1) * 256 + tid];
            float s = __uint_as_float((unsigned)(v & 0xffffffffu));
            const int col = (int)(v >> 32);
            s = (e < cnt) ? s : NEG_BIG;               // mask exhausted lanes
            const bool p = s > curmin;
            const float cmkey = p ? curmin : 3.0e38f;  // never matches when !p
#pragma unroll
            for (int j = 0; j < 16; ++j) {
                const bool hit = (tkS[j] == cmkey);
                tkS[j] = hit ? s : tkS[j];
                tkC[j] = hit ? col : tkC[j];
            }
            minTree();
            v = vn;
        }
        cnt = 0;
    };

    for (int gi = 0; gi < NGRP; ++gi) {
        const int s0 = split * SPLITLEN + gi * BN;
        // Stage 32-row k-tile hi/lo (pre-swizzled source -> linear LDS dest
        // realizes chunk ^= (row&31); conflict-free ds_read_b128).
#pragma unroll
        for (int i = 0; i < 4; ++i) {
            const int rho0 = wave * 8 + i * 2;     // covers rows rho0, rho0+1
            const int rho = rho0 + hk;
            const int gsrc = (s0 + rho) * EMB + ((r ^ (rho & 31)) << 3);
            gload_lds16(kh + gsrc, &Bh[rho0 * 256]);
            gload_lds16(kl + gsrc, &Bl[rho0 * 256]);
        }
        __syncthreads();   // staged (compiler drains vmcnt before barrier)

        // 3 independent fp16x3 chains -> issue-bound, not latency-bound.
        f32x16 aHH = {}, aLH = {}, aHL = {};
        __builtin_amdgcn_s_setprio(1);
#pragma unroll
        for (int kst = 0; kst < 16; ++kst) {
            const int slice = kst * 2 + hk;
            const int addr = r * 256 + ((slice ^ r) << 3);
            const f16x8 k_h = *(const f16x8*)&Bh[addr];
            const f16x8 k_l = *(const f16x8*)&Bl[addr];
            aHH = __builtin_amdgcn_mfma_f32_32x32x16_f16(k_h, ah[kst], aHH, 0, 0, 0);
            aLH = __builtin_amdgcn_mfma_f32_32x32x16_f16(k_l, ah[kst], aLH, 0, 0, 0);
            aHL = __builtin_amdgcn_mfma_f32_32x32x16_f16(k_h, al[kst], aHL, 0, 0, 0);
        }
        __builtin_amdgcn_s_setprio(0);

        if (gi == 0) {
            // Fill: first 16 candidates initialize the list directly.
#pragma unroll
            for (int j = 0; j < 16; ++j) {
                tkS[j] = (aHH[j] + aLH[j] + aHL[j]) * 0.0625f;
                tkC[j] = (j & 3) + 8 * (j >> 2) + rowoff0;
            }
            minTree();
        } else {
            const int base_col = gi * BN + rowoff0;
            // Branchless filter to per-thread stack (8B/lane stride: conflict-free).
#pragma unroll
            for (int j = 0; j < 16; ++j) {
                const float s = (aHH[j] + aLH[j] + aHL[j]) * 0.0625f;
                const int col = base_col + (j & 3) + 8 * (j >> 2);
                const bool p = s > curmin;
                const unsigned long long ev =
                    ((unsigned long long)(unsigned)col << 32) | (unsigned long long)__float_as_uint(s);
                stk[cnt * 256 + tid] = ev;      // unconditional; slop slot CAP
                cnt += p ? 1 : 0;
            }
            if (__any(cnt > 0)) rebuild();       // drain every group (CAP=16)
        }
        __syncthreads();   // all waves done reading Bh/Bl before restage
    }

    // Merge hk halves: lane r and lane r+32 hold two 16-lists for row qbase+r.
#pragma unroll
    for (int j = 0; j < 16; ++j) {
        const float os = __shfl_xor(tkS[j], 32);
        const int oc = __shfl_xor(tkC[j], 32);
        const bool p = os > curmin;
        const float cmkey = p ? curmin : 3.0e38f;
#pragma unroll
        for (int t = 0; t < 16; ++t) {
            const bool hit = (tkS[t] == cmkey);
            tkS[t] = hit ? os : tkS[t];
            tkC[t] = hit ? oc : tkC[t];
        }
        minTree();
    }

    if (lane < 32) {
        const int row = qbase + r;
#pragma unroll
        for (int j = 0; j < 16; ++j) {
            const int o = (row * NSPLIT + split) * TOPKK + j;
            part_sc[o] = tkS[j];
            part_id[o] = split * SPLITLEN + tkC[j];
        }
    }
}

// ---------------------------------------------------------------------------
// Merge 128 partials/row -> global top-16 -> softmax -> weighted gather of v.
// One wave per ego row (4 rows/block), 2048 blocks.
// ---------------------------------------------------------------------------
__global__ __launch_bounds__(256) void merge_kernel(
    const float* __restrict__ part_sc, const int* __restrict__ part_id,
    const float* __restrict__ v, float* __restrict__ out)
{
    __shared__ float ssel[4][16];
    __shared__ int   isel[4][16];
    const int tid = threadIdx.x, lane = tid & 63, wave = tid >> 6;
    const int row = blockIdx.x * 4 + wave;

    float c0 = part_sc[row * 128 + lane];
    float c1 = part_sc[row * 128 + 64 + lane];
    int   i0 = part_id[row * 128 + lane];
    int   i1 = part_id[row * 128 + 64 + lane];
    float m = 0.f;

    for (int t = 0; t < 16; ++t) {
        const bool sel1 = (c1 > c0) || (c1 == c0 && i1 < i0);
        float bs = sel1 ? c1 : c0;
        int   bid = sel1 ? i1 : i0;
#pragma unroll
        for (int o = 1; o < 64; o <<= 1) {
            const float os = __shfl_xor(bs, o);
            const int oid = __shfl_xor(bid, o);
            if (os > bs || (os == bs && oid < bid)) { bs = os; bid = oid; }
        }
        if (t == 0) m = bs;
        if (lane == 0) { ssel[wave][t] = bs; isel[wave][t] = bid; }
        if (i0 == bid) c0 = NEG_BIG;
        if (i1 == bid) c1 = NEG_BIG;
    }
    __syncthreads();

    float e[16]; float denom = 0.f;
#pragma unroll
    for (int t = 0; t < 16; ++t) { e[t] = expf(ssel[wave][t] - m); denom += e[t]; }
    const float inv = 1.0f / denom;

    float a0 = 0.f, a1 = 0.f, a2 = 0.f, a3 = 0.f;
    for (int t = 0; t < 16; ++t) {       // rank order == reference sum order
        const float w = e[t] * inv;
        const float* vp = v + (long)isel[wave][t] * EMB;
        a0 += w * vp[lane];
        a1 += w * vp[lane + 64];
        a2 += w * vp[lane + 128];
        a3 += w * vp[lane + 192];
    }
    out[row * EMB + lane]       = a0;
    out[row * EMB + lane + 64]  = a1;
    out[row * EMB + lane + 128] = a2;
    out[row * EMB + lane + 192] = a3;
}

// ---------------------------------------------------------------------------
extern "C" void kernel_launch(void* const* d_in, const int* in_sizes, int n_in,
                              void* d_out, int out_size, void* d_ws, size_t ws_size,
                              hipStream_t stream) {
    (void)in_sizes; (void)n_in; (void)out_size; (void)ws_size;
    const float* ego  = (const float*)d_in[0];
    const float* side = (const float*)d_in[1];
    const float* rel  = (const float*)d_in[2];
    const float* Wq   = (const float*)d_in[3];
    const float* bq   = (const float*)d_in[4];
    const float* Wk   = (const float*)d_in[5];
    const float* bk   = (const float*)d_in[6];
    const float* Wv   = (const float*)d_in[7];
    const float* bv   = (const float*)d_in[8];

    char* ws = (char*)d_ws;                      // 32MB used
    _Float16* qh = (_Float16*)ws;                // 4MB each
    _Float16* ql = qh + (size_t)NEGO * EMB;
    _Float16* kh = ql + (size_t)NEGO * EMB;
    _Float16* kl = kh + (size_t)NEGO * EMB;
    float* vbuf    = (float*)(ws + 16u * 1024 * 1024);   // 8MB
    float* part_sc = (float*)(ws + 24u * 1024 * 1024);   // 4MB
    int*   part_id = (int*)  (ws + 28u * 1024 * 1024);   // 4MB
    float* out = (float*)d_out;

    proj_kernel<<<dim3(NEGO / BM, 3), dim3(256), 0, stream>>>(
        ego, side, rel, Wq, bq, Wk, bk, Wv, bv, qh, ql, kh, kl, vbuf);
    scores_topk_kernel<<<dim3(NEGO / BM * NSPLIT), dim3(256), 0, stream>>>(
        qh, ql, kh, kl, part_sc, part_id);
    merge_kernel<<<dim3(NEGO / 4), dim3(256), 0, stream>>>(
        part_sc, part_id, vbuf, out);
}

// Round 10
// 266.504 us; speedup vs baseline: 1.0165x; 1.0165x over previous
//
#include <hip/hip_runtime.h>
#include <hip/hip_bf16.h>

// ---------------------------------------------------------------------------
// SparseKnowledgeAttention: q=ego@Wq.T+bq; k=(side*rel)@Wk.T+bk; v=side@Wv.T+bv
// scores=q@k.T/16 -> top16/row -> softmax -> weighted gather of v.
// fp16x3 split-precision MFMA (f32-exact scores), swapped operands
// (S^T = K·Q^T -> candidates lane-local). 2-phase pipelined K-loop:
// STAGE(t+1) issued BEFORE compute(t), one __syncthreads() per tile.
// Per-lane register top-16 + LDS survivor stack drained every group.
// hk-half merge uses a SNAPSHOT of the partner list (fix for the in-place
// cross-mutation dup bug that broke rounds 8/9 deterministically).
// grid 256 = 1 block/CU; K-split pinned per XCD (L2-resident).
// ---------------------------------------------------------------------------

#define EMB 256
#define NEGO 8192
#define NSIDE 8192
#define TOPKK 16
#define NSPLIT 4
#define SPLITLEN (NSIDE / NSPLIT)   // 2048
#define BM 128                      // ego rows per block (4 waves x 32)
#define BN 32                       // side rows per group
#define NGRP (SPLITLEN / BN)        // 64 groups per block
#define CAP 16                      // stack capacity (alloc 17: slop slot)

typedef _Float16 f16x8 __attribute__((ext_vector_type(8)));
typedef float f32x16 __attribute__((ext_vector_type(16)));

#define NEG_BIG (-3.402823466e38f)

__device__ __forceinline__ void gload_lds16(const _Float16* g, _Float16* l) {
    __builtin_amdgcn_global_load_lds((const __attribute__((address_space(1))) void*)g,
                                     (__attribute__((address_space(3))) void*)l, 16, 0, 0);
}

__device__ __forceinline__ void split8(const float* xv, f16x8& hi, f16x8& lo) {
#pragma unroll
    for (int j = 0; j < 8; ++j) {
        float x = xv[j];
        _Float16 h = (_Float16)x;
        hi[j] = h;
        lo[j] = (_Float16)(x - (float)h);
    }
}

// ---------------------------------------------------------------------------
// Projection kernel: C = X @ W.T + b  via fp16x3 MFMA. z = 0:q, 1:k, 2:v.
// grid (64, 3), block 256. Outputs: q,k as linear f16 hi/lo pairs; v as f32.
// ---------------------------------------------------------------------------
__global__ __launch_bounds__(256, 1) void proj_kernel(
    const float* __restrict__ ego, const float* __restrict__ side, const float* __restrict__ rel,
    const float* __restrict__ Wq, const float* __restrict__ bq,
    const float* __restrict__ Wk, const float* __restrict__ bk,
    const float* __restrict__ Wv, const float* __restrict__ bv,
    _Float16* __restrict__ qh, _Float16* __restrict__ ql,
    _Float16* __restrict__ kh, _Float16* __restrict__ kl,
    float* __restrict__ vout)
{
    __shared__ __align__(16) _Float16 Wh[64 * 256];   // 32KB, chunk-swizzled
    __shared__ __align__(16) _Float16 Wl[64 * 256];   // 32KB

    const int z = blockIdx.y;
    const float* X; const float* W; const float* bias;
    if (z == 0)      { X = ego;  W = Wq; bias = bq; }
    else if (z == 1) { X = side; W = Wk; bias = bk; }
    else             { X = side; W = Wv; bias = bv; }

    const int tid = threadIdx.x, lane = tid & 63, wave = tid >> 6;
    const int hk = lane >> 5, r = lane & 31;
    const int arow = blockIdx.x * BM + wave * 32 + r;

    f16x8 ah[16], al[16];
#pragma unroll
    for (int kst = 0; kst < 16; ++kst) {
        float xv[8];
        const float* p = X + arow * EMB + kst * 16 + hk * 8;
        const float4 x0 = *(const float4*)p;
        const float4 x1 = *(const float4*)(p + 4);
        xv[0]=x0.x; xv[1]=x0.y; xv[2]=x0.z; xv[3]=x0.w;
        xv[4]=x1.x; xv[5]=x1.y; xv[6]=x1.z; xv[7]=x1.w;
        if (z == 1) {
            const float* pr = rel + arow * EMB + kst * 16 + hk * 8;
            const float4 r0 = *(const float4*)pr;
            const float4 r1 = *(const float4*)(pr + 4);
            xv[0]*=r0.x; xv[1]*=r0.y; xv[2]*=r0.z; xv[3]*=r0.w;
            xv[4]*=r1.x; xv[5]*=r1.y; xv[6]*=r1.z; xv[7]*=r1.w;
        }
        split8(xv, ah[kst], al[kst]);
    }

    for (int nt = 0; nt < 4; ++nt) {
        __syncthreads();
#pragma unroll
        for (int i = 0; i < 8; ++i) {
            const int rowi = wave * 16 + i * 2 + hk;
            const int c = r;
            const float* wp = W + (nt * 64 + rowi) * EMB + ((c ^ (rowi & 31)) << 3);
            float xv[8];
            const float4 w0 = *(const float4*)wp;
            const float4 w1 = *(const float4*)(wp + 4);
            xv[0]=w0.x; xv[1]=w0.y; xv[2]=w0.z; xv[3]=w0.w;
            xv[4]=w1.x; xv[5]=w1.y; xv[6]=w1.z; xv[7]=w1.w;
            f16x8 h8, l8;
            split8(xv, h8, l8);
            *(f16x8*)&Wh[rowi * 256 + c * 8] = h8;
            *(f16x8*)&Wl[rowi * 256 + c * 8] = l8;
        }
        __syncthreads();

        f32x16 acc0 = {}, acc1 = {};
#pragma unroll
        for (int kst = 0; kst < 16; ++kst) {
            const int cc = kst * 2 + hk;
            const f16x8 bh0 = *(const f16x8*)&Wh[r * 256 + ((cc ^ r) << 3)];
            const f16x8 bl0 = *(const f16x8*)&Wl[r * 256 + ((cc ^ r) << 3)];
            const f16x8 bh1 = *(const f16x8*)&Wh[(32 + r) * 256 + ((cc ^ r) << 3)];
            const f16x8 bl1 = *(const f16x8*)&Wl[(32 + r) * 256 + ((cc ^ r) << 3)];
            acc0 = __builtin_amdgcn_mfma_f32_32x32x16_f16(ah[kst], bh0, acc0, 0, 0, 0);
            acc0 = __builtin_amdgcn_mfma_f32_32x32x16_f16(al[kst], bh0, acc0, 0, 0, 0);
            acc0 = __builtin_amdgcn_mfma_f32_32x32x16_f16(ah[kst], bl0, acc0, 0, 0, 0);
            acc1 = __builtin_amdgcn_mfma_f32_32x32x16_f16(ah[kst], bh1, acc1, 0, 0, 0);
            acc1 = __builtin_amdgcn_mfma_f32_32x32x16_f16(al[kst], bh1, acc1, 0, 0, 0);
            acc1 = __builtin_amdgcn_mfma_f32_32x32x16_f16(ah[kst], bl1, acc1, 0, 0, 0);
        }

#pragma unroll
        for (int reg = 0; reg < 16; ++reg) {
            const int crow = (reg & 3) + 8 * (reg >> 2) + 4 * hk;
            const int grow = blockIdx.x * BM + wave * 32 + crow;
            const int col0 = nt * 64 + r;
            const int col1 = nt * 64 + 32 + r;
            const float v0 = acc0[reg] + bias[col0];
            const float v1 = acc1[reg] + bias[col1];
            if (z < 2) {
                _Float16* oh = (z == 0) ? qh : kh;
                _Float16* ol = (z == 0) ? ql : kl;
                _Float16 h0 = (_Float16)v0;
                oh[grow * EMB + col0] = h0;
                ol[grow * EMB + col0] = (_Float16)(v0 - (float)h0);
                _Float16 h1 = (_Float16)v1;
                oh[grow * EMB + col1] = h1;
                ol[grow * EMB + col1] = (_Float16)(v1 - (float)h1);
            } else {
                vout[grow * EMB + col0] = v0;
                vout[grow * EMB + col1] = v1;
            }
        }
    }
}

// ---------------------------------------------------------------------------
// Fused scores + top-16, 2-phase pipelined. grid 256 (XCD-pinned split),
// block 256 (4 waves x 32 ego rows).
// ---------------------------------------------------------------------------
__global__ __launch_bounds__(256, 1) void scores_topk_kernel(
    const _Float16* __restrict__ qh, const _Float16* __restrict__ ql,
    const _Float16* __restrict__ kh, const _Float16* __restrict__ kl,
    float* __restrict__ part_sc, int* __restrict__ part_id)
{
    __shared__ __align__(16) _Float16 Bh[2 * BN * 256];    // 32KB dbuf k-tile (hi)
    __shared__ __align__(16) _Float16 Bl[2 * BN * 256];    // 32KB (lo)
    __shared__ unsigned long long stk[(CAP + 1) * 256];    // 34.8KB survivor stacks

    const int tid = threadIdx.x, lane = tid & 63, wave = tid >> 6;
    const int hk = lane >> 5, r = lane & 31;
    // XCD pinning: hw round-robins blocks over XCDs (xcd = blk%8). Map so each
    // XCD's 32 blocks share one K-split (2MB hi+lo, L2-resident). Bijective.
    const int split = (blockIdx.x & 7) >> 1;                     // 0..3
    const int bx = ((blockIdx.x >> 3) << 1) | (blockIdx.x & 1);  // 0..63
    const int qbase = bx * BM + wave * 32;
    const int rowoff0 = 4 * hk;

    // Per-lane register top-16 (distinct sentinels: value-keyed replace-min).
    float tkS[16]; int tkC[16];
#pragma unroll
    for (int j = 0; j < 16; ++j) { tkS[j] = -3.0e38f - (float)j * 1.0e30f; tkC[j] = 0x7fffffff; }
    float curmin = NEG_BIG;
    int cnt = 0;

    // Q fragments (row qbase+r) in registers — exact B-operand layout.
    f16x8 ah[16], al[16];
#pragma unroll
    for (int kst = 0; kst < 16; ++kst) {
        ah[kst] = *(const f16x8*)(qh + (qbase + r) * EMB + kst * 16 + hk * 8);
        al[kst] = *(const f16x8*)(ql + (qbase + r) * EMB + kst * 16 + hk * 8);
    }

    auto minTree = [&]() {
        float m0 = fminf(tkS[0], tkS[1]),  m1 = fminf(tkS[2], tkS[3]);
        float m2 = fminf(tkS[4], tkS[5]),  m3 = fminf(tkS[6], tkS[7]);
        float m4 = fminf(tkS[8], tkS[9]),  m5 = fminf(tkS[10], tkS[11]);
        float m6 = fminf(tkS[12], tkS[13]), m7 = fminf(tkS[14], tkS[15]);
        m0 = fminf(m0, m1); m2 = fminf(m2, m3); m4 = fminf(m4, m5); m6 = fminf(m6, m7);
        curmin = fminf(fminf(m0, m2), fminf(m4, m6));
    };

    // Ballot-free drain: wave-max(cnt) once, counted loop, next-entry preload
    // (slop slot CAP makes e+1 always in-bounds).
    auto rebuild = [&]() {
        int mc = cnt;
#pragma unroll
        for (int o = 32; o; o >>= 1) { const int t = __shfl_xor(mc, o); mc = t > mc ? t : mc; }
        unsigned long long v = stk[tid];
        for (int e = 0; e < mc; ++e) {
            const unsigned long long vn = stk[(e + 1) * 256 + tid];
            float s = __uint_as_float((unsigned)(v & 0xffffffffu));
            const int col = (int)(v >> 32);
            s = (e < cnt) ? s : NEG_BIG;               // mask exhausted lanes
            const bool p = s > curmin;
            const float cmkey = p ? curmin : 3.0e38f;  // never matches when !p
#pragma unroll
            for (int j = 0; j < 16; ++j) {
                const bool hit = (tkS[j] == cmkey);
                tkS[j] = hit ? s : tkS[j];
                tkC[j] = hit ? col : tkC[j];
            }
            minTree();
            v = vn;
        }
        cnt = 0;
    };

    // Stage group t's 32-row k-tile (hi+lo) into dbuf half b. Pre-swizzled
    // source -> linear LDS dest realizes chunk ^= (row&31): conflict-free
    // ds_read_b128. LDS dest is wave-uniform (hk only affects the source).
#define STAGE(t, b) do {                                                        \
        const int s0_ = split * SPLITLEN + (t) * BN;                            \
        _Float16* bh_ = &Bh[(b) * BN * 256];                                    \
        _Float16* bl_ = &Bl[(b) * BN * 256];                                    \
        _Pragma("unroll")                                                       \
        for (int i_ = 0; i_ < 4; ++i_) {                                        \
            const int rho0_ = wave * 8 + i_ * 2;                                \
            const int rho_ = rho0_ + hk;                                        \
            const int gsrc_ = (s0_ + rho_) * EMB + ((r ^ (rho_ & 31)) << 3);    \
            gload_lds16(kh + gsrc_, bh_ + rho0_ * 256);                         \
            gload_lds16(kl + gsrc_, bl_ + rho0_ * 256);                         \
        }                                                                       \
    } while (0)

    STAGE(0, 0);
    __syncthreads();   // prologue: tile 0 fully landed (vmcnt(0) drain)

    for (int gi = 0; gi < NGRP; ++gi) {
        // Issue next tile's loads FIRST; they fly during this tile's compute
        // and are drained by the __syncthreads at the END of this iteration.
        if (gi + 1 < NGRP) STAGE(gi + 1, (gi + 1) & 1);

        const _Float16* bh = &Bh[(gi & 1) * BN * 256];
        const _Float16* bl = &Bl[(gi & 1) * BN * 256];

        // 3 independent fp16x3 chains -> issue-bound, not latency-bound.
        f32x16 aHH = {}, aLH = {}, aHL = {};
#pragma unroll
        for (int kst = 0; kst < 16; ++kst) {
            const int slice = kst * 2 + hk;
            const int addr = r * 256 + ((slice ^ r) << 3);
            const f16x8 k_h = *(const f16x8*)&bh[addr];
            const f16x8 k_l = *(const f16x8*)&bl[addr];
            aHH = __builtin_amdgcn_mfma_f32_32x32x16_f16(k_h, ah[kst], aHH, 0, 0, 0);
            aLH = __builtin_amdgcn_mfma_f32_32x32x16_f16(k_l, ah[kst], aLH, 0, 0, 0);
            aHL = __builtin_amdgcn_mfma_f32_32x32x16_f16(k_h, al[kst], aHL, 0, 0, 0);
        }

        if (gi == 0) {
            // Fill: first 16 candidates initialize the list directly.
#pragma unroll
            for (int j = 0; j < 16; ++j) {
                tkS[j] = (aHH[j] + aLH[j] + aHL[j]) * 0.0625f;
                tkC[j] = (j & 3) + 8 * (j >> 2) + rowoff0;
            }
            minTree();
        } else {
            const int base_col = gi * BN + rowoff0;
            // Branchless filter to per-thread stack (8B/lane stride: conflict-free).
#pragma unroll
            for (int j = 0; j < 16; ++j) {
                const float s = (aHH[j] + aLH[j] + aHL[j]) * 0.0625f;
                const int col = base_col + (j & 3) + 8 * (j >> 2);
                const bool p = s > curmin;
                const unsigned long long ev =
                    ((unsigned long long)(unsigned)col << 32) | (unsigned long long)__float_as_uint(s);
                stk[cnt * 256 + tid] = ev;      // unconditional; slop slot CAP
                cnt += p ? 1 : 0;
            }
            if (__any(cnt > 0)) rebuild();       // drain every group (CAP=16)
        }

        // One barrier per tile: drains this iteration's prefetch loads
        // (vmcnt(0)) AND gates buffer reuse (full __syncthreads semantics).
        __syncthreads();
    }
#undef STAGE

    // Merge hk halves. FIX (rounds 8/9 bug): SNAPSHOT the partner's list via
    // shfl BEFORE any mutation. In-place mutual mutation let a lane receive
    // back its own already-inserted entry (partner's min-slot is value-keyed,
    // lands at any index) -> duplicate + lost union entry. Snapshot makes both
    // sides merge the partner's ORIGINAL 16; candidate sets are disjoint, so
    // the result is the exact top-16 of the union.
    {
        float osv[16]; int ocv[16];
#pragma unroll
        for (int j = 0; j < 16; ++j) {
            osv[j] = __shfl_xor(tkS[j], 32);
            ocv[j] = __shfl_xor(tkC[j], 32);
        }
#pragma unroll
        for (int j = 0; j < 16; ++j) {
            const bool p = osv[j] > curmin;
            const float cmkey = p ? curmin : 3.0e38f;
#pragma unroll
            for (int t = 0; t < 16; ++t) {
                const bool hit = (tkS[t] == cmkey);
                tkS[t] = hit ? osv[j] : tkS[t];
                tkC[t] = hit ? ocv[j] : tkC[t];
            }
            minTree();
        }
    }

    if (lane < 32) {
        const int row = qbase + r;
#pragma unroll
        for (int j = 0; j < 16; ++j) {
            const int o = (row * NSPLIT + split) * TOPKK + j;
            part_sc[o] = tkS[j];
            part_id[o] = split * SPLITLEN + tkC[j];
        }
    }
}

// ---------------------------------------------------------------------------
// Merge 64 partials/row -> global top-16 -> softmax -> weighted gather of v.
// One wave per ego row (4 rows/block), 2048 blocks.
// ---------------------------------------------------------------------------
__global__ __launch_bounds__(256) void merge_kernel(
    const float* __restrict__ part_sc, const int* __restrict__ part_id,
    const float* __restrict__ v, float* __restrict__ out)
{
    __shared__ float ssel[4][16];
    __shared__ int   isel[4][16];
    const int tid = threadIdx.x, lane = tid & 63, wave = tid >> 6;
    const int row = blockIdx.x * 4 + wave;

    float cs = part_sc[row * 64 + lane];
    int cid = part_id[row * 64 + lane];
    float m = 0.f;

    for (int t = 0; t < 16; ++t) {
        float bs = cs; int bid = cid;
#pragma unroll
        for (int o = 1; o < 64; o <<= 1) {
            const float os = __shfl_xor(bs, o);
            const int oid = __shfl_xor(bid, o);
            if (os > bs || (os == bs && oid < bid)) { bs = os; bid = oid; }
        }
        if (t == 0) m = bs;
        if (cid == bid) {                 // unique owner (ids are distinct)
            ssel[wave][t] = cs;
            isel[wave][t] = cid;
            cs = NEG_BIG; cid = 0x7fffffff;
        }
    }
    __syncthreads();

    float e[16]; float denom = 0.f;
#pragma unroll
    for (int t = 0; t < 16; ++t) { e[t] = expf(ssel[wave][t] - m); denom += e[t]; }
    const float inv = 1.0f / denom;

    float a0 = 0.f, a1 = 0.f, a2 = 0.f, a3 = 0.f;
    for (int t = 0; t < 16; ++t) {       // rank order == reference sum order
        const float w = e[t] * inv;
        const float* vp = v + (long)isel[wave][t] * EMB;
        a0 += w * vp[lane];
        a1 += w * vp[lane + 64];
        a2 += w * vp[lane + 128];
        a3 += w * vp[lane + 192];
    }
    out[row * EMB + lane]       = a0;
    out[row * EMB + lane + 64]  = a1;
    out[row * EMB + lane + 128] = a2;
    out[row * EMB + lane + 192] = a3;
}

// ---------------------------------------------------------------------------
extern "C" void kernel_launch(void* const* d_in, const int* in_sizes, int n_in,
                              void* d_out, int out_size, void* d_ws, size_t ws_size,
                              hipStream_t stream) {
    (void)in_sizes; (void)n_in; (void)out_size; (void)ws_size;
    const float* ego  = (const float*)d_in[0];
    const float* side = (const float*)d_in[1];
    const float* rel  = (const float*)d_in[2];
    const float* Wq   = (const float*)d_in[3];
    const float* bq   = (const float*)d_in[4];
    const float* Wk   = (const float*)d_in[5];
    const float* bk   = (const float*)d_in[6];
    const float* Wv   = (const float*)d_in[7];
    const float* bv   = (const float*)d_in[8];

    char* ws = (char*)d_ws;                      // 28MB used
    _Float16* qh = (_Float16*)ws;                // 4MB each
    _Float16* ql = qh + (size_t)NEGO * EMB;
    _Float16* kh = ql + (size_t)NEGO * EMB;
    _Float16* kl = kh + (size_t)NEGO * EMB;
    float* vbuf    = (float*)(ws + 16u * 1024 * 1024);   // 8MB
    float* part_sc = (float*)(ws + 24u * 1024 * 1024);   // 2MB
    int*   part_id = (int*)  (ws + 26u * 1024 * 1024);   // 2MB
    float* out = (float*)d_out;

    proj_kernel<<<dim3(NEGO / BM, 3), dim3(256), 0, stream>>>(
        ego, side, rel, Wq, bq, Wk, bk, Wv, bv, qh, ql, kh, kl, vbuf);
    scores_topk_kernel<<<dim3(NEGO / BM * NSPLIT), dim3(256), 0, stream>>>(
        qh, ql, kh, kl, part_sc, part_id);
    merge_kernel<<<dim3(NEGO / 4), dim3(256), 0, stream>>>(
        part_sc, part_id, vbuf, out);
}

// Round 11
// 234.577 us; speedup vs baseline: 1.1548x; 1.1361x over previous
//
#include <hip/hip_runtime.h>
#include <hip/hip_bf16.h>

// ---------------------------------------------------------------------------
// SparseKnowledgeAttention: q=ego@Wq.T+bq; k=(side*rel)@Wk.T+bk; v=side@Wv.T+bv
// scores=q@k.T/16 -> top16/row -> softmax -> weighted gather of v.
// fp16x3 split-precision MFMA (f32-exact scores), swapped operands
// (S^T = K·Q^T -> candidates lane-local). Round 11 = round-6 structure
// (NSPLIT=8, 2 blocks/CU = 2 waves/SIMD) + 2-phase dbuf prefetch pipeline
// (round-10 verified scheme) + compact 6B survivor stack (CAP=8, drain per
// 8-candidate half) + deferred 1/16 scaling + snapshot hk-merge (r10 fix).
// LDS 79.4KB -> 2 blocks/CU. K-split pinned per XCD (L2-resident).
// ---------------------------------------------------------------------------

#define EMB 256
#define NEGO 8192
#define NSIDE 8192
#define TOPKK 16
#define NSPLIT 8
#define SPLITLEN (NSIDE / NSPLIT)   // 1024
#define BM 128                      // ego rows per block (4 waves x 32)
#define BN 32                       // side rows per group
#define NGRP (SPLITLEN / BN)        // 32 groups per block
#define CAP 8                       // stack capacity (alloc 9: slop slot)

typedef _Float16 f16x8 __attribute__((ext_vector_type(8)));
typedef float f32x16 __attribute__((ext_vector_type(16)));

#define NEG_BIG (-3.402823466e38f)

__device__ __forceinline__ void gload_lds16(const _Float16* g, _Float16* l) {
    __builtin_amdgcn_global_load_lds((const __attribute__((address_space(1))) void*)g,
                                     (__attribute__((address_space(3))) void*)l, 16, 0, 0);
}

__device__ __forceinline__ void split8(const float* xv, f16x8& hi, f16x8& lo) {
#pragma unroll
    for (int j = 0; j < 8; ++j) {
        float x = xv[j];
        _Float16 h = (_Float16)x;
        hi[j] = h;
        lo[j] = (_Float16)(x - (float)h);
    }
}

// ---------------------------------------------------------------------------
// Projection kernel: C = X @ W.T + b  via fp16x3 MFMA. z = 0:q, 1:k, 2:v.
// grid (64, 3), block 256. Outputs: q,k as linear f16 hi/lo pairs; v as f32.
// ---------------------------------------------------------------------------
__global__ __launch_bounds__(256, 1) void proj_kernel(
    const float* __restrict__ ego, const float* __restrict__ side, const float* __restrict__ rel,
    const float* __restrict__ Wq, const float* __restrict__ bq,
    const float* __restrict__ Wk, const float* __restrict__ bk,
    const float* __restrict__ Wv, const float* __restrict__ bv,
    _Float16* __restrict__ qh, _Float16* __restrict__ ql,
    _Float16* __restrict__ kh, _Float16* __restrict__ kl,
    float* __restrict__ vout)
{
    __shared__ __align__(16) _Float16 Wh[64 * 256];   // 32KB, chunk-swizzled
    __shared__ __align__(16) _Float16 Wl[64 * 256];   // 32KB

    const int z = blockIdx.y;
    const float* X; const float* W; const float* bias;
    if (z == 0)      { X = ego;  W = Wq; bias = bq; }
    else if (z == 1) { X = side; W = Wk; bias = bk; }
    else             { X = side; W = Wv; bias = bv; }

    const int tid = threadIdx.x, lane = tid & 63, wave = tid >> 6;
    const int hk = lane >> 5, r = lane & 31;
    const int arow = blockIdx.x * BM + wave * 32 + r;

    f16x8 ah[16], al[16];
#pragma unroll
    for (int kst = 0; kst < 16; ++kst) {
        float xv[8];
        const float* p = X + arow * EMB + kst * 16 + hk * 8;
        const float4 x0 = *(const float4*)p;
        const float4 x1 = *(const float4*)(p + 4);
        xv[0]=x0.x; xv[1]=x0.y; xv[2]=x0.z; xv[3]=x0.w;
        xv[4]=x1.x; xv[5]=x1.y; xv[6]=x1.z; xv[7]=x1.w;
        if (z == 1) {
            const float* pr = rel + arow * EMB + kst * 16 + hk * 8;
            const float4 r0 = *(const float4*)pr;
            const float4 r1 = *(const float4*)(pr + 4);
            xv[0]*=r0.x; xv[1]*=r0.y; xv[2]*=r0.z; xv[3]*=r0.w;
            xv[4]*=r1.x; xv[5]*=r1.y; xv[6]*=r1.z; xv[7]*=r1.w;
        }
        split8(xv, ah[kst], al[kst]);
    }

    for (int nt = 0; nt < 4; ++nt) {
        __syncthreads();
#pragma unroll
        for (int i = 0; i < 8; ++i) {
            const int rowi = wave * 16 + i * 2 + hk;
            const int c = r;
            const float* wp = W + (nt * 64 + rowi) * EMB + ((c ^ (rowi & 31)) << 3);
            float xv[8];
            const float4 w0 = *(const float4*)wp;
            const float4 w1 = *(const float4*)(wp + 4);
            xv[0]=w0.x; xv[1]=w0.y; xv[2]=w0.z; xv[3]=w0.w;
            xv[4]=w1.x; xv[5]=w1.y; xv[6]=w1.z; xv[7]=w1.w;
            f16x8 h8, l8;
            split8(xv, h8, l8);
            *(f16x8*)&Wh[rowi * 256 + c * 8] = h8;
            *(f16x8*)&Wl[rowi * 256 + c * 8] = l8;
        }
        __syncthreads();

        f32x16 acc0 = {}, acc1 = {};
#pragma unroll
        for (int kst = 0; kst < 16; ++kst) {
            const int cc = kst * 2 + hk;
            const f16x8 bh0 = *(const f16x8*)&Wh[r * 256 + ((cc ^ r) << 3)];
            const f16x8 bl0 = *(const f16x8*)&Wl[r * 256 + ((cc ^ r) << 3)];
            const f16x8 bh1 = *(const f16x8*)&Wh[(32 + r) * 256 + ((cc ^ r) << 3)];
            const f16x8 bl1 = *(const f16x8*)&Wl[(32 + r) * 256 + ((cc ^ r) << 3)];
            acc0 = __builtin_amdgcn_mfma_f32_32x32x16_f16(ah[kst], bh0, acc0, 0, 0, 0);
            acc0 = __builtin_amdgcn_mfma_f32_32x32x16_f16(al[kst], bh0, acc0, 0, 0, 0);
            acc0 = __builtin_amdgcn_mfma_f32_32x32x16_f16(ah[kst], bl0, acc0, 0, 0, 0);
            acc1 = __builtin_amdgcn_mfma_f32_32x32x16_f16(ah[kst], bh1, acc1, 0, 0, 0);
            acc1 = __builtin_amdgcn_mfma_f32_32x32x16_f16(al[kst], bh1, acc1, 0, 0, 0);
            acc1 = __builtin_amdgcn_mfma_f32_32x32x16_f16(ah[kst], bl1, acc1, 0, 0, 0);
        }

#pragma unroll
        for (int reg = 0; reg < 16; ++reg) {
            const int crow = (reg & 3) + 8 * (reg >> 2) + 4 * hk;
            const int grow = blockIdx.x * BM + wave * 32 + crow;
            const int col0 = nt * 64 + r;
            const int col1 = nt * 64 + 32 + r;
            const float v0 = acc0[reg] + bias[col0];
            const float v1 = acc1[reg] + bias[col1];
            if (z < 2) {
                _Float16* oh = (z == 0) ? qh : kh;
                _Float16* ol = (z == 0) ? ql : kl;
                _Float16 h0 = (_Float16)v0;
                oh[grow * EMB + col0] = h0;
                ol[grow * EMB + col0] = (_Float16)(v0 - (float)h0);
                _Float16 h1 = (_Float16)v1;
                oh[grow * EMB + col1] = h1;
                ol[grow * EMB + col1] = (_Float16)(v1 - (float)h1);
            } else {
                vout[grow * EMB + col0] = v0;
                vout[grow * EMB + col1] = v1;
            }
        }
    }
}

// ---------------------------------------------------------------------------
// Fused scores + top-16, 2-phase pipelined, 2 blocks/CU.
// grid 512 (split = blk&7 -> XCD-pinned), block 256 (4 waves x 32 ego rows).
// ---------------------------------------------------------------------------
__global__ __launch_bounds__(256, 2) void scores_topk_kernel(
    const _Float16* __restrict__ qh, const _Float16* __restrict__ ql,
    const _Float16* __restrict__ kh, const _Float16* __restrict__ kl,
    float* __restrict__ part_sc, int* __restrict__ part_id)
{
    __shared__ __align__(16) _Float16 Bh[2 * BN * 256];    // 32KB dbuf k-tile (hi)
    __shared__ __align__(16) _Float16 Bl[2 * BN * 256];    // 32KB (lo)
    __shared__ float          stkS[(CAP + 1) * 256];       // 9.2KB survivor scores
    __shared__ unsigned short stkC[(CAP + 1) * 256];       // 4.6KB survivor cols
    // total LDS = 79.4KB -> 2 blocks/CU

    const int tid = threadIdx.x, lane = tid & 63, wave = tid >> 6;
    const int hk = lane >> 5, r = lane & 31;
    const int split = blockIdx.x & 7;          // XCD-pinned K-split (2MB, L2-res)
    const int bx = blockIdx.x >> 3;            // ego block 0..63
    const int qbase = bx * BM + wave * 32;
    const int rowoff0 = 4 * hk;

    // Per-lane register top-16 (distinct sentinels: value-keyed replace-min).
    // Scores kept RAW (un-scaled); exact pow2 scale applied at final write.
    float tkS[16]; int tkC[16];
#pragma unroll
    for (int j = 0; j < 16; ++j) { tkS[j] = -3.0e38f - (float)j * 1.0e30f; tkC[j] = 0x7fffffff; }
    float curmin = NEG_BIG;
    int cnt = 0;

    // Q fragments (row qbase+r) in registers — exact B-operand layout.
    f16x8 ah[16], al[16];
#pragma unroll
    for (int kst = 0; kst < 16; ++kst) {
        ah[kst] = *(const f16x8*)(qh + (qbase + r) * EMB + kst * 16 + hk * 8);
        al[kst] = *(const f16x8*)(ql + (qbase + r) * EMB + kst * 16 + hk * 8);
    }

    auto minTree = [&]() {
        float m0 = fminf(tkS[0], tkS[1]),  m1 = fminf(tkS[2], tkS[3]);
        float m2 = fminf(tkS[4], tkS[5]),  m3 = fminf(tkS[6], tkS[7]);
        float m4 = fminf(tkS[8], tkS[9]),  m5 = fminf(tkS[10], tkS[11]);
        float m6 = fminf(tkS[12], tkS[13]), m7 = fminf(tkS[14], tkS[15]);
        m0 = fminf(m0, m1); m2 = fminf(m2, m3); m4 = fminf(m4, m5); m6 = fminf(m6, m7);
        curmin = fminf(fminf(m0, m2), fminf(m4, m6));
    };

    // Ballot-free drain: wave-max(cnt) once, counted loop over entries.
    auto rebuild = [&]() {
        int mc = cnt;
#pragma unroll
        for (int o = 32; o; o >>= 1) { const int t = __shfl_xor(mc, o); mc = t > mc ? t : mc; }
        for (int e = 0; e < mc; ++e) {
            float s = stkS[e * 256 + tid];
            const int col = stkC[e * 256 + tid];
            s = (e < cnt) ? s : NEG_BIG;               // mask exhausted lanes
            const bool p = s > curmin;
            const float cmkey = p ? curmin : 3.0e38f;  // never matches when !p
#pragma unroll
            for (int j = 0; j < 16; ++j) {
                const bool hit = (tkS[j] == cmkey);
                tkS[j] = hit ? s : tkS[j];
                tkC[j] = hit ? col : tkC[j];
            }
            minTree();
        }
        cnt = 0;
    };

    // Stage group t's 32-row k-tile (hi+lo) into dbuf half b. Pre-swizzled
    // source -> linear LDS dest realizes chunk ^= (row&31): conflict-free
    // ds_read_b128. LDS dest is wave-uniform (hk only affects the source).
#define STAGE(t, b) do {                                                        \
        const int s0_ = split * SPLITLEN + (t) * BN;                            \
        _Float16* bh_ = &Bh[(b) * BN * 256];                                    \
        _Float16* bl_ = &Bl[(b) * BN * 256];                                    \
        _Pragma("unroll")                                                       \
        for (int i_ = 0; i_ < 4; ++i_) {                                        \
            const int rho0_ = wave * 8 + i_ * 2;                                \
            const int rho_ = rho0_ + hk;                                        \
            const int gsrc_ = (s0_ + rho_) * EMB + ((r ^ (rho_ & 31)) << 3);    \
            gload_lds16(kh + gsrc_, bh_ + rho0_ * 256);                         \
            gload_lds16(kl + gsrc_, bl_ + rho0_ * 256);                         \
        }                                                                       \
    } while (0)

    STAGE(0, 0);
    __syncthreads();   // prologue: tile 0 fully landed (vmcnt(0) drain)

    for (int gi = 0; gi < NGRP; ++gi) {
        // Issue next tile's loads FIRST; they fly during this tile's compute
        // and are drained by the __syncthreads at the END of this iteration.
        if (gi + 1 < NGRP) STAGE(gi + 1, (gi + 1) & 1);

        const _Float16* bh = &Bh[(gi & 1) * BN * 256];
        const _Float16* bl = &Bl[(gi & 1) * BN * 256];

        // 3 independent fp16x3 chains -> issue-bound, not latency-bound.
        f32x16 aHH = {}, aLH = {}, aHL = {};
#pragma unroll
        for (int kst = 0; kst < 16; ++kst) {
            const int slice = kst * 2 + hk;
            const int addr = r * 256 + ((slice ^ r) << 3);
            const f16x8 k_h = *(const f16x8*)&bh[addr];
            const f16x8 k_l = *(const f16x8*)&bl[addr];
            aHH = __builtin_amdgcn_mfma_f32_32x32x16_f16(k_h, ah[kst], aHH, 0, 0, 0);
            aLH = __builtin_amdgcn_mfma_f32_32x32x16_f16(k_l, ah[kst], aLH, 0, 0, 0);
            aHL = __builtin_amdgcn_mfma_f32_32x32x16_f16(k_h, al[kst], aHL, 0, 0, 0);
        }

        if (gi == 0) {
            // Fill: first 16 candidates initialize the list directly (raw).
#pragma unroll
            for (int j = 0; j < 16; ++j) {
                tkS[j] = aHH[j] + aLH[j] + aHL[j];
                tkC[j] = (j & 3) + 8 * (j >> 2) + rowoff0;
            }
            minTree();
        } else {
            const int base_col = gi * BN + rowoff0;
            // Two 8-candidate halves; branchless filter to per-thread stack
            // (CAP=8 + slop slot), drain between halves. 4B+2B lanes: 2-way
            // bank aliasing = free.
#pragma unroll
            for (int h = 0; h < 2; ++h) {
#pragma unroll
                for (int jj = 0; jj < 8; ++jj) {
                    const int j = h * 8 + jj;
                    const float s = aHH[j] + aLH[j] + aHL[j];   // raw score*16
                    const int col = base_col + (j & 3) + 8 * (j >> 2);
                    const bool p = s > curmin;
                    stkS[cnt * 256 + tid] = s;      // unconditional; slop slot
                    stkC[cnt * 256 + tid] = (unsigned short)col;
                    cnt += p ? 1 : 0;
                }
                if (__any(cnt > 0)) rebuild();
            }
        }

        // One barrier per tile: drains this iteration's prefetch loads
        // (vmcnt(0)) AND gates dbuf reuse (full __syncthreads semantics).
        __syncthreads();
    }
#undef STAGE

    // Merge hk halves via SNAPSHOT (r10 fix): both lanes merge the partner's
    // ORIGINAL 16; candidate sets are disjoint -> exact top-16 of the union.
    {
        float osv[16]; int ocv[16];
#pragma unroll
        for (int j = 0; j < 16; ++j) {
            osv[j] = __shfl_xor(tkS[j], 32);
            ocv[j] = __shfl_xor(tkC[j], 32);
        }
#pragma unroll
        for (int j = 0; j < 16; ++j) {
            const bool p = osv[j] > curmin;
            const float cmkey = p ? curmin : 3.0e38f;
#pragma unroll
            for (int t = 0; t < 16; ++t) {
                const bool hit = (tkS[t] == cmkey);
                tkS[t] = hit ? osv[j] : tkS[t];
                tkC[t] = hit ? ocv[j] : tkC[t];
            }
            minTree();
        }
    }

    if (lane < 32) {
        const int row = qbase + r;
#pragma unroll
        for (int j = 0; j < 16; ++j) {
            const int o = (row * NSPLIT + split) * TOPKK + j;
            part_sc[o] = tkS[j] * 0.0625f;     // exact pow2 scale at the end
            part_id[o] = split * SPLITLEN + tkC[j];
        }
    }
}

// ---------------------------------------------------------------------------
// Merge 128 partials/row -> global top-16 -> softmax -> weighted gather of v.
// One wave per ego row (4 rows/block), 2048 blocks.
// ---------------------------------------------------------------------------
__global__ __launch_bounds__(256) void merge_kernel(
    const float* __restrict__ part_sc, const int* __restrict__ part_id,
    const float* __restrict__ v, float* __restrict__ out)
{
    __shared__ float ssel[4][16];
    __shared__ int   isel[4][16];
    const int tid = threadIdx.x, lane = tid & 63, wave = tid >> 6;
    const int row = blockIdx.x * 4 + wave;

    float c0 = part_sc[row * 128 + lane];
    float c1 = part_sc[row * 128 + 64 + lane];
    int   i0 = part_id[row * 128 + lane];
    int   i1 = part_id[row * 128 + 64 + lane];
    float m = 0.f;

    for (int t = 0; t < 16; ++t) {
        const bool sel1 = (c1 > c0) || (c1 == c0 && i1 < i0);
        float bs = sel1 ? c1 : c0;
        int   bid = sel1 ? i1 : i0;
#pragma unroll
        for (int o = 1; o < 64; o <<= 1) {
            const float os = __shfl_xor(bs, o);
            const int oid = __shfl_xor(bid, o);
            if (os > bs || (os == bs && oid < bid)) { bs = os; bid = oid; }
        }
        if (t == 0) m = bs;
        if (lane == 0) { ssel[wave][t] = bs; isel[wave][t] = bid; }
        if (i0 == bid) c0 = NEG_BIG;
        if (i1 == bid) c1 = NEG_BIG;
    }
    __syncthreads();

    float e[16]; float denom = 0.f;
#pragma unroll
    for (int t = 0; t < 16; ++t) { e[t] = expf(ssel[wave][t] - m); denom += e[t]; }
    const float inv = 1.0f / denom;

    float a0 = 0.f, a1 = 0.f, a2 = 0.f, a3 = 0.f;
    for (int t = 0; t < 16; ++t) {       // rank order == reference sum order
        const float w = e[t] * inv;
        const float* vp = v + (long)isel[wave][t] * EMB;
        a0 += w * vp[lane];
        a1 += w * vp[lane + 64];
        a2 += w * vp[lane + 128];
        a3 += w * vp[lane + 192];
    }
    out[row * EMB + lane]       = a0;
    out[row * EMB + lane + 64]  = a1;
    out[row * EMB + lane + 128] = a2;
    out[row * EMB + lane + 192] = a3;
}

// ---------------------------------------------------------------------------
extern "C" void kernel_launch(void* const* d_in, const int* in_sizes, int n_in,
                              void* d_out, int out_size, void* d_ws, size_t ws_size,
                              hipStream_t stream) {
    (void)in_sizes; (void)n_in; (void)out_size; (void)ws_size;
    const float* ego  = (const float*)d_in[0];
    const float* side = (const float*)d_in[1];
    const float* rel  = (const float*)d_in[2];
    const float* Wq   = (const float*)d_in[3];
    const float* bq   = (const float*)d_in[4];
    const float* Wk   = (const float*)d_in[5];
    const float* bk   = (const float*)d_in[6];
    const float* Wv   = (const float*)d_in[7];
    const float* bv   = (const float*)d_in[8];

    char* ws = (char*)d_ws;                      // 32MB used
    _Float16* qh = (_Float16*)ws;                // 4MB each
    _Float16* ql = qh + (size_t)NEGO * EMB;
    _Float16* kh = ql + (size_t)NEGO * EMB;
    _Float16* kl = kh + (size_t)NEGO * EMB;
    float* vbuf    = (float*)(ws + 16u * 1024 * 1024);   // 8MB
    float* part_sc = (float*)(ws + 24u * 1024 * 1024);   // 4MB
    int*   part_id = (int*)  (ws + 28u * 1024 * 1024);   // 4MB
    float* out = (float*)d_out;

    proj_kernel<<<dim3(NEGO / BM, 3), dim3(256), 0, stream>>>(
        ego, side, rel, Wq, bq, Wk, bk, Wv, bv, qh, ql, kh, kl, vbuf);
    scores_topk_kernel<<<dim3(NEGO / BM * NSPLIT), dim3(256), 0, stream>>>(
        qh, ql, kh, kl, part_sc, part_id);
    merge_kernel<<<dim3(NEGO / 4), dim3(256), 0, stream>>>(
        part_sc, part_id, vbuf, out);
}

// Round 12
// 234.179 us; speedup vs baseline: 1.1568x; 1.0017x over previous
//
#include <hip/hip_runtime.h>
#include <hip/hip_bf16.h>

// ---------------------------------------------------------------------------
// SparseKnowledgeAttention: q=ego@Wq.T+bq; k=(side*rel)@Wk.T+bk; v=side@Wv.T+bv
// scores=q@k.T/16 -> top16/row -> softmax -> weighted gather of v.
// fp16x3 split-precision MFMA (f32-exact scores), swapped operands
// (S^T = K·Q^T -> candidates lane-local). Round 12 = round 11 + forced
// waves_per_eu(2,2): firm 256-VGPR budget so the Q fragments (128 VGPR)
// stay register-resident instead of being rematerialized from global every
// group (r6/7/11 all showed VGPR=128 => per-group Q reload ~2GB L2 traffic).
// LDS 79.4KB -> 2 blocks/CU. K-split pinned per XCD (L2-resident).
// ---------------------------------------------------------------------------

#define EMB 256
#define NEGO 8192
#define NSIDE 8192
#define TOPKK 16
#define NSPLIT 8
#define SPLITLEN (NSIDE / NSPLIT)   // 1024
#define BM 128                      // ego rows per block (4 waves x 32)
#define BN 32                       // side rows per group
#define NGRP (SPLITLEN / BN)        // 32 groups per block
#define CAP 8                       // stack capacity (alloc 9: slop slot)

typedef _Float16 f16x8 __attribute__((ext_vector_type(8)));
typedef float f32x16 __attribute__((ext_vector_type(16)));

#define NEG_BIG (-3.402823466e38f)

__device__ __forceinline__ void gload_lds16(const _Float16* g, _Float16* l) {
    __builtin_amdgcn_global_load_lds((const __attribute__((address_space(1))) void*)g,
                                     (__attribute__((address_space(3))) void*)l, 16, 0, 0);
}

__device__ __forceinline__ void split8(const float* xv, f16x8& hi, f16x8& lo) {
#pragma unroll
    for (int j = 0; j < 8; ++j) {
        float x = xv[j];
        _Float16 h = (_Float16)x;
        hi[j] = h;
        lo[j] = (_Float16)(x - (float)h);
    }
}

// ---------------------------------------------------------------------------
// Projection kernel: C = X @ W.T + b  via fp16x3 MFMA. z = 0:q, 1:k, 2:v.
// grid (64, 3), block 256. Outputs: q,k as linear f16 hi/lo pairs; v as f32.
// ---------------------------------------------------------------------------
__global__ __launch_bounds__(256, 1) void proj_kernel(
    const float* __restrict__ ego, const float* __restrict__ side, const float* __restrict__ rel,
    const float* __restrict__ Wq, const float* __restrict__ bq,
    const float* __restrict__ Wk, const float* __restrict__ bk,
    const float* __restrict__ Wv, const float* __restrict__ bv,
    _Float16* __restrict__ qh, _Float16* __restrict__ ql,
    _Float16* __restrict__ kh, _Float16* __restrict__ kl,
    float* __restrict__ vout)
{
    __shared__ __align__(16) _Float16 Wh[64 * 256];   // 32KB, chunk-swizzled
    __shared__ __align__(16) _Float16 Wl[64 * 256];   // 32KB

    const int z = blockIdx.y;
    const float* X; const float* W; const float* bias;
    if (z == 0)      { X = ego;  W = Wq; bias = bq; }
    else if (z == 1) { X = side; W = Wk; bias = bk; }
    else             { X = side; W = Wv; bias = bv; }

    const int tid = threadIdx.x, lane = tid & 63, wave = tid >> 6;
    const int hk = lane >> 5, r = lane & 31;
    const int arow = blockIdx.x * BM + wave * 32 + r;

    f16x8 ah[16], al[16];
#pragma unroll
    for (int kst = 0; kst < 16; ++kst) {
        float xv[8];
        const float* p = X + arow * EMB + kst * 16 + hk * 8;
        const float4 x0 = *(const float4*)p;
        const float4 x1 = *(const float4*)(p + 4);
        xv[0]=x0.x; xv[1]=x0.y; xv[2]=x0.z; xv[3]=x0.w;
        xv[4]=x1.x; xv[5]=x1.y; xv[6]=x1.z; xv[7]=x1.w;
        if (z == 1) {
            const float* pr = rel + arow * EMB + kst * 16 + hk * 8;
            const float4 r0 = *(const float4*)pr;
            const float4 r1 = *(const float4*)(pr + 4);
            xv[0]*=r0.x; xv[1]*=r0.y; xv[2]*=r0.z; xv[3]*=r0.w;
            xv[4]*=r1.x; xv[5]*=r1.y; xv[6]*=r1.z; xv[7]*=r1.w;
        }
        split8(xv, ah[kst], al[kst]);
    }

    for (int nt = 0; nt < 4; ++nt) {
        __syncthreads();
#pragma unroll
        for (int i = 0; i < 8; ++i) {
            const int rowi = wave * 16 + i * 2 + hk;
            const int c = r;
            const float* wp = W + (nt * 64 + rowi) * EMB + ((c ^ (rowi & 31)) << 3);
            float xv[8];
            const float4 w0 = *(const float4*)wp;
            const float4 w1 = *(const float4*)(wp + 4);
            xv[0]=w0.x; xv[1]=w0.y; xv[2]=w0.z; xv[3]=w0.w;
            xv[4]=w1.x; xv[5]=w1.y; xv[6]=w1.z; xv[7]=w1.w;
            f16x8 h8, l8;
            split8(xv, h8, l8);
            *(f16x8*)&Wh[rowi * 256 + c * 8] = h8;
            *(f16x8*)&Wl[rowi * 256 + c * 8] = l8;
        }
        __syncthreads();

        f32x16 acc0 = {}, acc1 = {};
#pragma unroll
        for (int kst = 0; kst < 16; ++kst) {
            const int cc = kst * 2 + hk;
            const f16x8 bh0 = *(const f16x8*)&Wh[r * 256 + ((cc ^ r) << 3)];
            const f16x8 bl0 = *(const f16x8*)&Wl[r * 256 + ((cc ^ r) << 3)];
            const f16x8 bh1 = *(const f16x8*)&Wh[(32 + r) * 256 + ((cc ^ r) << 3)];
            const f16x8 bl1 = *(const f16x8*)&Wl[(32 + r) * 256 + ((cc ^ r) << 3)];
            acc0 = __builtin_amdgcn_mfma_f32_32x32x16_f16(ah[kst], bh0, acc0, 0, 0, 0);
            acc0 = __builtin_amdgcn_mfma_f32_32x32x16_f16(al[kst], bh0, acc0, 0, 0, 0);
            acc0 = __builtin_amdgcn_mfma_f32_32x32x16_f16(ah[kst], bl0, acc0, 0, 0, 0);
            acc1 = __builtin_amdgcn_mfma_f32_32x32x16_f16(ah[kst], bh1, acc1, 0, 0, 0);
            acc1 = __builtin_amdgcn_mfma_f32_32x32x16_f16(al[kst], bh1, acc1, 0, 0, 0);
            acc1 = __builtin_amdgcn_mfma_f32_32x32x16_f16(ah[kst], bl1, acc1, 0, 0, 0);
        }

#pragma unroll
        for (int reg = 0; reg < 16; ++reg) {
            const int crow = (reg & 3) + 8 * (reg >> 2) + 4 * hk;
            const int grow = blockIdx.x * BM + wave * 32 + crow;
            const int col0 = nt * 64 + r;
            const int col1 = nt * 64 + 32 + r;
            const float v0 = acc0[reg] + bias[col0];
            const float v1 = acc1[reg] + bias[col1];
            if (z < 2) {
                _Float16* oh = (z == 0) ? qh : kh;
                _Float16* ol = (z == 0) ? ql : kl;
                _Float16 h0 = (_Float16)v0;
                oh[grow * EMB + col0] = h0;
                ol[grow * EMB + col0] = (_Float16)(v0 - (float)h0);
                _Float16 h1 = (_Float16)v1;
                oh[grow * EMB + col1] = h1;
                ol[grow * EMB + col1] = (_Float16)(v1 - (float)h1);
            } else {
                vout[grow * EMB + col0] = v0;
                vout[grow * EMB + col1] = v1;
            }
        }
    }
}

// ---------------------------------------------------------------------------
// Fused scores + top-16, 2-phase pipelined, 2 blocks/CU.
// grid 512 (split = blk&7 -> XCD-pinned), block 256 (4 waves x 32 ego rows).
// waves_per_eu(2,2): firm 256-VGPR budget -> Q fragments stay resident
// (no per-group rematerialized global reloads).
// ---------------------------------------------------------------------------
__global__ __launch_bounds__(256) __attribute__((amdgpu_waves_per_eu(2, 2)))
void scores_topk_kernel(
    const _Float16* __restrict__ qh, const _Float16* __restrict__ ql,
    const _Float16* __restrict__ kh, const _Float16* __restrict__ kl,
    float* __restrict__ part_sc, int* __restrict__ part_id)
{
    __shared__ __align__(16) _Float16 Bh[2 * BN * 256];    // 32KB dbuf k-tile (hi)
    __shared__ __align__(16) _Float16 Bl[2 * BN * 256];    // 32KB (lo)
    __shared__ float          stkS[(CAP + 1) * 256];       // 9.2KB survivor scores
    __shared__ unsigned short stkC[(CAP + 1) * 256];       // 4.6KB survivor cols
    // total LDS = 79.4KB -> 2 blocks/CU

    const int tid = threadIdx.x, lane = tid & 63, wave = tid >> 6;
    const int hk = lane >> 5, r = lane & 31;
    const int split = blockIdx.x & 7;          // XCD-pinned K-split (2MB, L2-res)
    const int bx = blockIdx.x >> 3;            // ego block 0..63
    const int qbase = bx * BM + wave * 32;
    const int rowoff0 = 4 * hk;

    // Per-lane register top-16 (distinct sentinels: value-keyed replace-min).
    // Scores kept RAW (un-scaled); exact pow2 scale applied at final write.
    float tkS[16]; int tkC[16];
#pragma unroll
    for (int j = 0; j < 16; ++j) { tkS[j] = -3.0e38f - (float)j * 1.0e30f; tkC[j] = 0x7fffffff; }
    float curmin = NEG_BIG;
    int cnt = 0;

    // Q fragments (row qbase+r) in registers — exact B-operand layout.
    f16x8 ah[16], al[16];
#pragma unroll
    for (int kst = 0; kst < 16; ++kst) {
        ah[kst] = *(const f16x8*)(qh + (qbase + r) * EMB + kst * 16 + hk * 8);
        al[kst] = *(const f16x8*)(ql + (qbase + r) * EMB + kst * 16 + hk * 8);
    }

    auto minTree = [&]() {
        float m0 = fminf(tkS[0], tkS[1]),  m1 = fminf(tkS[2], tkS[3]);
        float m2 = fminf(tkS[4], tkS[5]),  m3 = fminf(tkS[6], tkS[7]);
        float m4 = fminf(tkS[8], tkS[9]),  m5 = fminf(tkS[10], tkS[11]);
        float m6 = fminf(tkS[12], tkS[13]), m7 = fminf(tkS[14], tkS[15]);
        m0 = fminf(m0, m1); m2 = fminf(m2, m3); m4 = fminf(m4, m5); m6 = fminf(m6, m7);
        curmin = fminf(fminf(m0, m2), fminf(m4, m6));
    };

    // Ballot-free drain: wave-max(cnt) once, counted loop over entries.
    auto rebuild = [&]() {
        int mc = cnt;
#pragma unroll
        for (int o = 32; o; o >>= 1) { const int t = __shfl_xor(mc, o); mc = t > mc ? t : mc; }
        for (int e = 0; e < mc; ++e) {
            float s = stkS[e * 256 + tid];
            const int col = stkC[e * 256 + tid];
            s = (e < cnt) ? s : NEG_BIG;               // mask exhausted lanes
            const bool p = s > curmin;
            const float cmkey = p ? curmin : 3.0e38f;  // never matches when !p
#pragma unroll
            for (int j = 0; j < 16; ++j) {
                const bool hit = (tkS[j] == cmkey);
                tkS[j] = hit ? s : tkS[j];
                tkC[j] = hit ? col : tkC[j];
            }
            minTree();
        }
        cnt = 0;
    };

    // Stage group t's 32-row k-tile (hi+lo) into dbuf half b. Pre-swizzled
    // source -> linear LDS dest realizes chunk ^= (row&31): conflict-free
    // ds_read_b128. LDS dest is wave-uniform (hk only affects the source).
#define STAGE(t, b) do {                                                        \
        const int s0_ = split * SPLITLEN + (t) * BN;                            \
        _Float16* bh_ = &Bh[(b) * BN * 256];                                    \
        _Float16* bl_ = &Bl[(b) * BN * 256];                                    \
        _Pragma("unroll")                                                       \
        for (int i_ = 0; i_ < 4; ++i_) {                                        \
            const int rho0_ = wave * 8 + i_ * 2;                                \
            const int rho_ = rho0_ + hk;                                        \
            const int gsrc_ = (s0_ + rho_) * EMB + ((r ^ (rho_ & 31)) << 3);    \
            gload_lds16(kh + gsrc_, bh_ + rho0_ * 256);                         \
            gload_lds16(kl + gsrc_, bl_ + rho0_ * 256);                         \
        }                                                                       \
    } while (0)

    STAGE(0, 0);
    __syncthreads();   // prologue: tile 0 fully landed (vmcnt(0) drain)

    for (int gi = 0; gi < NGRP; ++gi) {
        // Issue next tile's loads FIRST; they fly during this tile's compute
        // and are drained by the __syncthreads at the END of this iteration.
        if (gi + 1 < NGRP) STAGE(gi + 1, (gi + 1) & 1);

        const _Float16* bh = &Bh[(gi & 1) * BN * 256];
        const _Float16* bl = &Bl[(gi & 1) * BN * 256];

        // 3 independent fp16x3 chains -> issue-bound, not latency-bound.
        f32x16 aHH = {}, aLH = {}, aHL = {};
#pragma unroll
        for (int kst = 0; kst < 16; ++kst) {
            const int slice = kst * 2 + hk;
            const int addr = r * 256 + ((slice ^ r) << 3);
            const f16x8 k_h = *(const f16x8*)&bh[addr];
            const f16x8 k_l = *(const f16x8*)&bl[addr];
            aHH = __builtin_amdgcn_mfma_f32_32x32x16_f16(k_h, ah[kst], aHH, 0, 0, 0);
            aLH = __builtin_amdgcn_mfma_f32_32x32x16_f16(k_l, ah[kst], aLH, 0, 0, 0);
            aHL = __builtin_amdgcn_mfma_f32_32x32x16_f16(k_h, al[kst], aHL, 0, 0, 0);
        }

        if (gi == 0) {
            // Fill: first 16 candidates initialize the list directly (raw).
#pragma unroll
            for (int j = 0; j < 16; ++j) {
                tkS[j] = aHH[j] + aLH[j] + aHL[j];
                tkC[j] = (j & 3) + 8 * (j >> 2) + rowoff0;
            }
            minTree();
        } else {
            const int base_col = gi * BN + rowoff0;
            // Two 8-candidate halves; branchless filter to per-thread stack
            // (CAP=8 + slop slot), drain between halves. 4B+2B lanes: 2-way
            // bank aliasing = free.
#pragma unroll
            for (int h = 0; h < 2; ++h) {
#pragma unroll
                for (int jj = 0; jj < 8; ++jj) {
                    const int j = h * 8 + jj;
                    const float s = aHH[j] + aLH[j] + aHL[j];   // raw score*16
                    const int col = base_col + (j & 3) + 8 * (j >> 2);
                    const bool p = s > curmin;
                    stkS[cnt * 256 + tid] = s;      // unconditional; slop slot
                    stkC[cnt * 256 + tid] = (unsigned short)col;
                    cnt += p ? 1 : 0;
                }
                if (__any(cnt > 0)) rebuild();
            }
        }

        // One barrier per tile: drains this iteration's prefetch loads
        // (vmcnt(0)) AND gates dbuf reuse (full __syncthreads semantics).
        __syncthreads();
    }
#undef STAGE

    // Merge hk halves via SNAPSHOT (r10 fix): both lanes merge the partner's
    // ORIGINAL 16; candidate sets are disjoint -> exact top-16 of the union.
    {
        float osv[16]; int ocv[16];
#pragma unroll
        for (int j = 0; j < 16; ++j) {
            osv[j] = __shfl_xor(tkS[j], 32);
            ocv[j] = __shfl_xor(tkC[j], 32);
        }
#pragma unroll
        for (int j = 0; j < 16; ++j) {
            const bool p = osv[j] > curmin;
            const float cmkey = p ? curmin : 3.0e38f;
#pragma unroll
            for (int t = 0; t < 16; ++t) {
                const bool hit = (tkS[t] == cmkey);
                tkS[t] = hit ? osv[j] : tkS[t];
                tkC[t] = hit ? ocv[j] : tkC[t];
            }
            minTree();
        }
    }

    if (lane < 32) {
        const int row = qbase + r;
#pragma unroll
        for (int j = 0; j < 16; ++j) {
            const int o = (row * NSPLIT + split) * TOPKK + j;
            part_sc[o] = tkS[j] * 0.0625f;     // exact pow2 scale at the end
            part_id[o] = split * SPLITLEN + tkC[j];
        }
    }
}

// ---------------------------------------------------------------------------
// Merge 128 partials/row -> global top-16 -> softmax -> weighted gather of v.
// One wave per ego row (4 rows/block), 2048 blocks.
// ---------------------------------------------------------------------------
__global__ __launch_bounds__(256) void merge_kernel(
    const float* __restrict__ part_sc, const int* __restrict__ part_id,
    const float* __restrict__ v, float* __restrict__ out)
{
    __shared__ float ssel[4][16];
    __shared__ int   isel[4][16];
    const int tid = threadIdx.x, lane = tid & 63, wave = tid >> 6;
    const int row = blockIdx.x * 4 + wave;

    float c0 = part_sc[row * 128 + lane];
    float c1 = part_sc[row * 128 + 64 + lane];
    int   i0 = part_id[row * 128 + lane];
    int   i1 = part_id[row * 128 + 64 + lane];
    float m = 0.f;

    for (int t = 0; t < 16; ++t) {
        const bool sel1 = (c1 > c0) || (c1 == c0 && i1 < i0);
        float bs = sel1 ? c1 : c0;
        int   bid = sel1 ? i1 : i0;
#pragma unroll
        for (int o = 1; o < 64; o <<= 1) {
            const float os = __shfl_xor(bs, o);
            const int oid = __shfl_xor(bid, o);
            if (os > bs || (os == bs && oid < bid)) { bs = os; bid = oid; }
        }
        if (t == 0) m = bs;
        if (lane == 0) { ssel[wave][t] = bs; isel[wave][t] = bid; }
        if (i0 == bid) c0 = NEG_BIG;
        if (i1 == bid) c1 = NEG_BIG;
    }
    __syncthreads();

    float e[16]; float denom = 0.f;
#pragma unroll
    for (int t = 0; t < 16; ++t) { e[t] = expf(ssel[wave][t] - m); denom += e[t]; }
    const float inv = 1.0f / denom;

    float a0 = 0.f, a1 = 0.f, a2 = 0.f, a3 = 0.f;
    for (int t = 0; t < 16; ++t) {       // rank order == reference sum order
        const float w = e[t] * inv;
        const float* vp = v + (long)isel[wave][t] * EMB;
        a0 += w * vp[lane];
        a1 += w * vp[lane + 64];
        a2 += w * vp[lane + 128];
        a3 += w * vp[lane + 192];
    }
    out[row * EMB + lane]       = a0;
    out[row * EMB + lane + 64]  = a1;
    out[row * EMB + lane + 128] = a2;
    out[row * EMB + lane + 192] = a3;
}

// ---------------------------------------------------------------------------
extern "C" void kernel_launch(void* const* d_in, const int* in_sizes, int n_in,
                              void* d_out, int out_size, void* d_ws, size_t ws_size,
                              hipStream_t stream) {
    (void)in_sizes; (void)n_in; (void)out_size; (void)ws_size;
    const float* ego  = (const float*)d_in[0];
    const float* side = (const float*)d_in[1];
    const float* rel  = (const float*)d_in[2];
    const float* Wq   = (const float*)d_in[3];
    const float* bq   = (const float*)d_in[4];
    const float* Wk   = (const float*)d_in[5];
    const float* bk   = (const float*)d_in[6];
    const float* Wv   = (const float*)d_in[7];
    const float* bv   = (const float*)d_in[8];

    char* ws = (char*)d_ws;                      // 32MB used
    _Float16* qh = (_Float16*)ws;                // 4MB each
    _Float16* ql = qh + (size_t)NEGO * EMB;
    _Float16* kh = ql + (size_t)NEGO * EMB;
    _Float16* kl = kh + (size_t)NEGO * EMB;
    float* vbuf    = (float*)(ws + 16u * 1024 * 1024);   // 8MB
    float* part_sc = (float*)(ws + 24u * 1024 * 1024);   // 4MB
    int*   part_id = (int*)  (ws + 28u * 1024 * 1024);   // 4MB
    float* out = (float*)d_out;

    proj_kernel<<<dim3(NEGO / BM, 3), dim3(256), 0, stream>>>(
        ego, side, rel, Wq, bq, Wk, bk, Wv, bv, qh, ql, kh, kl, vbuf);
    scores_topk_kernel<<<dim3(NEGO / BM * NSPLIT), dim3(256), 0, stream>>>(
        qh, ql, kh, kl, part_sc, part_id);
    merge_kernel<<<dim3(NEGO / 4), dim3(256), 0, stream>>>(
        part_sc, part_id, vbuf, out);
}